// Round 14
// baseline (154.162 us; speedup 1.0000x reference)
//
#include <hip/hip_runtime.h>

// ---------------------------------------------------------------------------
// TreeConv GNN. R13: deeper MLP on the two latency-bound phases.
//   - fused gathers: 8-deep edge unroll (fused1: 16 uint4 in flight/thread).
//   - partition: CHUNK 8192->2048 (196->782 blocks; was 0.77 blocks/CU).
//   Structure otherwise = R12 (64-node fused MFMA tiles, barriers after
//   every LDS phase, 7 launches).
// ---------------------------------------------------------------------------

#define NPB 256       // nodes per bucket (fill); bucket id = dst >> 8
#define NBMAX 512     // max buckets (n <= 131072)
#define CHUNK 2048    // edges per partition block

typedef __attribute__((ext_vector_type(8))) short short8;
typedef __attribute__((ext_vector_type(4))) float f32x4;

__device__ inline unsigned int bfbits(float f) {  // RNE f32 -> bf16 bits
  unsigned int x = __float_as_uint(f);
  return (x + 0x7fffu + ((x >> 16) & 1u)) >> 16;
}
__device__ inline unsigned int packbf(float a, float b) {
  return bfbits(a) | (bfbits(b) << 16);
}
__device__ inline float bflo(unsigned int u) {
  return __uint_as_float(u << 16);
}
__device__ inline float bfhi(unsigned int u) {
  return __uint_as_float(u & 0xffff0000u);
}

// ---------------- CSR build ----------------

__global__ __launch_bounds__(256) void bucket_hist_kernel(
    const int* __restrict__ dst, int* __restrict__ bcnt, int ne, int nb) {
  __shared__ int h[NBMAX];
  for (int i = threadIdx.x; i < nb; i += 256) h[i] = 0;
  __syncthreads();
  for (int e = blockIdx.x * 256 + threadIdx.x; e < ne; e += gridDim.x * 256)
    atomicAdd(&h[dst[e] >> 8], 1);
  __syncthreads();
  for (int i = threadIdx.x; i < nb; i += 256) {
    const int c = h[i];
    if (c) atomicAdd(&bcnt[i], c);
  }
}

__global__ __launch_bounds__(512) void bucket_scan_kernel(
    const int* __restrict__ bcnt, int* __restrict__ boff,
    int* __restrict__ bcur, int nb, int ne) {
  __shared__ int wsum[8];
  const int lane = threadIdx.x & 63;
  const int wid = threadIdx.x >> 6;
  const int v = (threadIdx.x < nb) ? bcnt[threadIdx.x] : 0;
  int x = v;
#pragma unroll
  for (int s = 1; s < 64; s <<= 1) {
    int t = __shfl_up(x, s, 64);
    if (lane >= s) x += t;
  }
  if (lane == 63) wsum[wid] = x;
  __syncthreads();
  if (wid == 0 && lane < 8) {
    int y = wsum[lane];
#pragma unroll
    for (int s = 1; s < 8; s <<= 1) {
      int t = __shfl_up(y, s, 64);
      if (lane >= s) y += t;
    }
    wsum[lane] = y;
  }
  __syncthreads();
  const int wbase = (wid == 0) ? 0 : wsum[wid - 1];
  const int excl = wbase + x - v;
  if (threadIdx.x < nb) {
    boff[threadIdx.x] = excl;
    bcur[threadIdx.x] = excl;
  }
  if (threadIdx.x == 0) boff[nb] = ne;
}

__global__ __launch_bounds__(256) void partition_kernel(
    const int* __restrict__ src, const int* __restrict__ dst,
    int* __restrict__ bcur, int* __restrict__ sorted, int ne, int nb) {
  __shared__ int hist[NBMAX];
  __shared__ int lbase[NBMAX];
  __shared__ int gbase[NBMAX];
  __shared__ int cur[NBMAX];
  __shared__ int vals[CHUNK];
  __shared__ unsigned short bins[CHUNK];

  const int tid = threadIdx.x;
  const int e0 = blockIdx.x * CHUNK;
  const int m = min(CHUNK, ne - e0);

  for (int i = tid; i < nb; i += 256) hist[i] = 0;
  __syncthreads();
  for (int i = tid; i < m; i += 256) atomicAdd(&hist[dst[e0 + i] >> 8], 1);
  __syncthreads();

  if (tid < 64) {
    int v8[8];
    int tot = 0;
#pragma unroll
    for (int k = 0; k < 8; k++) {
      const int b = tid * 8 + k;
      v8[k] = (b < nb) ? hist[b] : 0;
      tot += v8[k];
    }
    int x = tot;
#pragma unroll
    for (int s = 1; s < 64; s <<= 1) {
      int t = __shfl_up(x, s, 64);
      if ((tid & 63) >= s) x += t;
    }
    int run = x - tot;
#pragma unroll
    for (int k = 0; k < 8; k++) {
      const int b = tid * 8 + k;
      if (b < nb) {
        lbase[b] = run;
        run += v8[k];
      }
    }
  }
  __syncthreads();

  for (int b = tid; b < nb; b += 256) {
    const int c = hist[b];
    cur[b] = lbase[b];
    gbase[b] = c ? atomicAdd(&bcur[b], c) : 0;
  }
  __syncthreads();

  for (int i = tid; i < m; i += 256) {
    const int s = src[e0 + i];
    const int d = dst[e0 + i];
    const int b = d >> 8;
    const int p = atomicAdd(&cur[b], 1);
    vals[p] = s | ((d & 255) << 17);
    bins[p] = (unsigned short)b;
  }
  __syncthreads();

  for (int i = tid; i < m; i += 256) {
    const int b = bins[i];
    sorted[gbase[b] + (i - lbase[b])] = vals[i];
  }
}

__global__ __launch_bounds__(256) void fill_bucket_kernel(
    const int* __restrict__ sorted, const int* __restrict__ boff,
    int* __restrict__ off, int* __restrict__ csr, int n, int ne) {
  __shared__ int hist[NPB];
  __shared__ int cur[NPB];
  __shared__ int wsum[4];
  const int tid = threadIdx.x;
  const int b = blockIdx.x;
  const int e0 = boff[b];
  const int m = boff[b + 1] - e0;

  hist[tid] = 0;
  __syncthreads();
  for (int i = tid; i < m; i += 256) atomicAdd(&hist[sorted[e0 + i] >> 17], 1);
  __syncthreads();

  const int lane = tid & 63;
  const int wid = tid >> 6;
  const int v = hist[tid];
  int x = v;
#pragma unroll
  for (int s = 1; s < 64; s <<= 1) {
    int t = __shfl_up(x, s, 64);
    if (lane >= s) x += t;
  }
  if (lane == 63) wsum[wid] = x;
  __syncthreads();
  if (tid == 0) {
    int s = 0;
#pragma unroll
    for (int k = 0; k < 4; k++) {
      const int t = wsum[k];
      wsum[k] = s;
      s += t;
    }
  }
  __syncthreads();
  const int excl = wsum[wid] + x - v;
  cur[tid] = excl;
  const int node = b * NPB + tid;
  if (node < n) off[node] = e0 + excl;
  if (b == 0 && tid == 0) off[n] = ne;
  __syncthreads();

  for (int i = tid; i < m; i += 256) {
    const int pv = sorted[e0 + i];
    const int r = atomicAdd(&cur[pv >> 17], 1);
    csr[e0 + r] = pv & 0x1FFFF;
  }
}

// ---------------------------------------------------------------------------
// prep: block 0 -> weight repack + zero bcnt; blocks 1.. -> x to bf16.
// wfrag: [0,4)=W1_0 [4,12)=W2_0 [12,20)=W1_1 [20,28)=W2_1 [28,36)=CW1
// [36,38)=CW2(N=16).
// ---------------------------------------------------------------------------
__global__ __launch_bounds__(256) void prep_kernel(
    const float4* __restrict__ x, uint2* __restrict__ xbf, int n4,
    const float* __restrict__ w1_0, const float* __restrict__ w2_0,
    const float* __restrict__ w1_1, const float* __restrict__ w2_1,
    const float* __restrict__ cw1, const float* __restrict__ cw2,
    uint4* __restrict__ wfrag, int* __restrict__ bcnt, int nb) {
  if (blockIdx.x == 0) {
    for (int i = threadIdx.x; i < nb; i += 256) bcnt[i] = 0;
    for (int idx = threadIdx.x; idx < 38 * 64; idx += 256) {
      const int f = idx >> 6, l = idx & 63;
      const float* W;
      int N = 64, f0;
      if (f < 4) { W = w1_0; f0 = f; }
      else if (f < 12) { W = w2_0; f0 = f - 4; }
      else if (f < 20) { W = w1_1; f0 = f - 12; }
      else if (f < 28) { W = w2_1; f0 = f - 20; }
      else if (f < 36) { W = cw1; f0 = f - 28; }
      else { W = cw2; f0 = f - 36; N = 16; }
      int kb, t;
      if (N == 16) { kb = f0; t = 0; } else { kb = f0 >> 2; t = f0 & 3; }
      const int k0 = kb * 32 + (l >> 4) * 8;
      const int col = t * 16 + (l & 15);
      unsigned int p[4];
#pragma unroll
      for (int j = 0; j < 4; j++)
        p[j] =
            packbf(W[(k0 + 2 * j) * N + col], W[(k0 + 2 * j + 1) * N + col]);
      wfrag[idx] = make_uint4(p[0], p[1], p[2], p[3]);
    }
    return;
  }
  const int i = (blockIdx.x - 1) * 256 + threadIdx.x;
  if (i < n4) {
    const float4 v = x[i];
    xbf[i] = make_uint2(packbf(v.x, v.y), packbf(v.z, v.w));
  }
}

// ---------------------------------------------------------------------------
// Per-wave GEMM stage on 64-row LDS tiles: wave wid owns rows
// [16*wid, 16*wid+16). Caller must __syncthreads() between stages.
// ---------------------------------------------------------------------------
template <int KB, int NT, bool RELU>
__device__ inline void gemm_stage(const unsigned short* __restrict__ src,
                                  int srcs, unsigned short* __restrict__ dst,
                                  const short8* __restrict__ wfrag,
                                  const float* __restrict__ bias, int wid,
                                  int lane) {
  const int l15 = lane & 15, lh = lane >> 4;
  short8 bf[KB * NT];
#pragma unroll
  for (int f = 0; f < KB * NT; f++) bf[f] = wfrag[f * 64 + lane];
  f32x4 acc[NT];
#pragma unroll
  for (int t = 0; t < NT; t++) acc[t] = (f32x4){0.f, 0.f, 0.f, 0.f};
#pragma unroll
  for (int kb = 0; kb < KB; kb++) {
    const short8 a =
        *(const short8*)&src[(wid * 16 + l15) * srcs + kb * 32 + lh * 8];
#pragma unroll
    for (int t = 0; t < NT; t++)
      acc[t] = __builtin_amdgcn_mfma_f32_16x16x32_bf16(a, bf[kb * NT + t],
                                                       acc[t], 0, 0, 0);
  }
  float bv[NT];
#pragma unroll
  for (int t = 0; t < NT; t++) bv[t] = bias[t * 16 + l15];
#pragma unroll
  for (int t = 0; t < NT; t++)
#pragma unroll
    for (int r = 0; r < 4; r++) {
      float v = acc[t][r] + bv[t];
      if (RELU) v = fmaxf(v, 0.f);
      dst[(wid * 16 + lh * 4 + r) * 72 + t * 16 + l15] =
          (unsigned short)bfbits(v);
    }
}

// ---------------------------------------------------------------------------
// fused0: gather(xbf, D=32) -> GEMM(w1_0)+relu -> GEMM(w2_0) -> h0bf.
// 64 nodes/block, 4 threads/node (1 uint4 each), 8-deep edge unroll.
// ---------------------------------------------------------------------------
__global__ __launch_bounds__(256) void fused0_kernel(
    const uint4* __restrict__ xbf, const int* __restrict__ off,
    const int* __restrict__ csr, const short8* __restrict__ wf,
    const float* __restrict__ b1, const float* __restrict__ b2,
    uint4* __restrict__ h0bf, int n) {
  __shared__ unsigned short zsA[64 * 72];
  __shared__ unsigned short zsB[64 * 72];
  const int tid = threadIdx.x;
  const int lane = tid & 63;
  const int wid = tid >> 6;
  const int n0 = blockIdx.x * 64;

  {
    const int node = tid >> 2;
    const int q4 = tid & 3;
    const int g = n0 + node;
    float a[8];
#pragma unroll
    for (int i = 0; i < 8; i++) a[i] = 0.f;
    if (g < n) {
      const uint4 u = xbf[(size_t)g * 4 + q4];
      a[0] = bflo(u.x); a[1] = bfhi(u.x); a[2] = bflo(u.y); a[3] = bfhi(u.y);
      a[4] = bflo(u.z); a[5] = bfhi(u.z); a[6] = bflo(u.w); a[7] = bfhi(u.w);
      const int e0 = off[g], e1 = off[g + 1];
      int e = e0;
      for (; e + 7 < e1; e += 8) {
        int s[8];
#pragma unroll
        for (int j = 0; j < 8; j++) s[j] = csr[e + j];
        uint4 v[8];
#pragma unroll
        for (int j = 0; j < 8; j++) v[j] = xbf[(size_t)s[j] * 4 + q4];
#pragma unroll
        for (int j = 0; j < 8; j++) {
          a[0] += bflo(v[j].x); a[1] += bfhi(v[j].x);
          a[2] += bflo(v[j].y); a[3] += bfhi(v[j].y);
          a[4] += bflo(v[j].z); a[5] += bfhi(v[j].z);
          a[6] += bflo(v[j].w); a[7] += bfhi(v[j].w);
        }
      }
      for (; e < e1; ++e) {
        const uint4 u4 = xbf[(size_t)csr[e] * 4 + q4];
        a[0] += bflo(u4.x); a[1] += bfhi(u4.x);
        a[2] += bflo(u4.y); a[3] += bfhi(u4.y);
        a[4] += bflo(u4.z); a[5] += bfhi(u4.z);
        a[6] += bflo(u4.w); a[7] += bfhi(u4.w);
      }
    }
    uint4 w;
    w.x = packbf(a[0], a[1]); w.y = packbf(a[2], a[3]);
    w.z = packbf(a[4], a[5]); w.w = packbf(a[6], a[7]);
    *(uint4*)&zsA[node * 40 + q4 * 8] = w;
  }
  __syncthreads();
  gemm_stage<1, 4, true>(zsA, 40, zsB, wf + 0 * 64, b1, wid, lane);
  __syncthreads();
  gemm_stage<2, 4, false>(zsB, 72, zsA, wf + 4 * 64, b2, wid, lane);
  __syncthreads();

  for (int i = tid; i < 64 * 8; i += 256) {
    const int row = i >> 3, q = i & 7;
    if (n0 + row < n)
      ((short8*)h0bf)[(size_t)(n0 + row) * 8 + q] =
          *(const short8*)&zsA[row * 72 + q * 8];
  }
}

// ---------------------------------------------------------------------------
// fused1: gather(h0bf, D=64) -> GEMM(w1_1)+relu -> GEMM(w2_1) -> GEMM(cw1)
// +relu -> GEMM(cw2,N=16) -> out f32. 64 nodes/block, 4 threads/node
// (2 uint4 each), 8-deep edge unroll (16 uint4 in flight).
// ---------------------------------------------------------------------------
__global__ __launch_bounds__(256) void fused1_kernel(
    const uint4* __restrict__ hbf, const int* __restrict__ off,
    const int* __restrict__ csr, const short8* __restrict__ wf,
    const float* __restrict__ b1, const float* __restrict__ b2,
    const float* __restrict__ cb1, const float* __restrict__ cb2,
    float* __restrict__ out, int n) {
  __shared__ unsigned short zsA[64 * 72];
  __shared__ unsigned short zsB[64 * 72];
  const int tid = threadIdx.x;
  const int lane = tid & 63;
  const int wid = tid >> 6;
  const int n0 = blockIdx.x * 64;
  const int l15 = lane & 15, lh = lane >> 4;

  {
    const int node = tid >> 2;
    const int q4 = tid & 3;
    const int g = n0 + node;
    float a[16];
#pragma unroll
    for (int i = 0; i < 16; i++) a[i] = 0.f;
    if (g < n) {
      const uint4* base = hbf + (size_t)g * 8 + q4 * 2;
      const uint4 ua = base[0], ub = base[1];
      a[0] = bflo(ua.x); a[1] = bfhi(ua.x); a[2] = bflo(ua.y); a[3] = bfhi(ua.y);
      a[4] = bflo(ua.z); a[5] = bfhi(ua.z); a[6] = bflo(ua.w); a[7] = bfhi(ua.w);
      a[8] = bflo(ub.x); a[9] = bfhi(ub.x); a[10] = bflo(ub.y); a[11] = bfhi(ub.y);
      a[12] = bflo(ub.z); a[13] = bfhi(ub.z); a[14] = bflo(ub.w); a[15] = bfhi(ub.w);
      const int e0 = off[g], e1 = off[g + 1];
      int e = e0;
      for (; e + 7 < e1; e += 8) {
        int s[8];
#pragma unroll
        for (int j = 0; j < 8; j++) s[j] = csr[e + j];
        uint4 va[8], vb[8];
#pragma unroll
        for (int j = 0; j < 8; j++) {
          const uint4* p = hbf + (size_t)s[j] * 8 + q4 * 2;
          va[j] = p[0];
          vb[j] = p[1];
        }
#pragma unroll
        for (int j = 0; j < 8; j++) {
          a[0] += bflo(va[j].x); a[1] += bfhi(va[j].x);
          a[2] += bflo(va[j].y); a[3] += bfhi(va[j].y);
          a[4] += bflo(va[j].z); a[5] += bfhi(va[j].z);
          a[6] += bflo(va[j].w); a[7] += bfhi(va[j].w);
          a[8] += bflo(vb[j].x); a[9] += bfhi(vb[j].x);
          a[10] += bflo(vb[j].y); a[11] += bfhi(vb[j].y);
          a[12] += bflo(vb[j].z); a[13] += bfhi(vb[j].z);
          a[14] += bflo(vb[j].w); a[15] += bfhi(vb[j].w);
        }
      }
      for (; e < e1; ++e) {
        const uint4* p = hbf + (size_t)csr[e] * 8 + q4 * 2;
        const uint4 wa = p[0], wb = p[1];
        a[0] += bflo(wa.x); a[1] += bfhi(wa.x);
        a[2] += bflo(wa.y); a[3] += bfhi(wa.y);
        a[4] += bflo(wa.z); a[5] += bfhi(wa.z);
        a[6] += bflo(wa.w); a[7] += bfhi(wa.w);
        a[8] += bflo(wb.x); a[9] += bfhi(wb.x);
        a[10] += bflo(wb.y); a[11] += bfhi(wb.y);
        a[12] += bflo(wb.z); a[13] += bfhi(wb.z);
        a[14] += bflo(wb.w); a[15] += bfhi(wb.w);
      }
    }
#pragma unroll
    for (int h = 0; h < 2; h++) {
      uint4 w;
      w.x = packbf(a[h * 8 + 0], a[h * 8 + 1]);
      w.y = packbf(a[h * 8 + 2], a[h * 8 + 3]);
      w.z = packbf(a[h * 8 + 4], a[h * 8 + 5]);
      w.w = packbf(a[h * 8 + 6], a[h * 8 + 7]);
      *(uint4*)&zsA[node * 72 + q4 * 16 + h * 8] = w;
    }
  }
  __syncthreads();
  gemm_stage<2, 4, true>(zsA, 72, zsB, wf + 12 * 64, b1, wid, lane);   // z1
  __syncthreads();
  gemm_stage<2, 4, false>(zsB, 72, zsA, wf + 20 * 64, b2, wid, lane);  // h1
  __syncthreads();
  gemm_stage<2, 4, true>(zsA, 72, zsB, wf + 28 * 64, cb1, wid, lane);  // z2
  __syncthreads();

  // GEMM4: K=64, N=16 (cw2) -> f32 out
  {
    const short8 bf0 = wf[36 * 64 + lane];
    const short8 bf1 = wf[37 * 64 + lane];
    f32x4 acc = (f32x4){0.f, 0.f, 0.f, 0.f};
#pragma unroll
    for (int kb = 0; kb < 2; kb++) {
      const short8 a =
          *(const short8*)&zsB[(wid * 16 + l15) * 72 + kb * 32 + lh * 8];
      acc = __builtin_amdgcn_mfma_f32_16x16x32_bf16(a, kb ? bf1 : bf0, acc, 0,
                                                    0, 0);
    }
    __syncthreads();
    float* zf = (float*)zsA;  // [64][20] f32
    const float bb = cb2[l15];
#pragma unroll
    for (int r = 0; r < 4; r++)
      zf[(wid * 16 + lh * 4 + r) * 20 + l15] = acc[r] + bb;
    __syncthreads();
    for (int i = tid; i < 256; i += 256) {
      const int row = i >> 2, q = i & 3;
      if (n0 + row < n)
        ((float4*)out)[(size_t)(n0 + row) * 4 + q] =
            *(const float4*)&zf[row * 20 + q * 4];
    }
  }
}

extern "C" void kernel_launch(void* const* d_in, const int* in_sizes, int n_in,
                              void* d_out, int out_size, void* d_ws,
                              size_t ws_size, hipStream_t stream) {
  const float* x = (const float*)d_in[0];
  const int* ei = (const int*)d_in[1];
  const float* w1_0 = (const float*)d_in[2];
  const float* b1_0 = (const float*)d_in[3];
  const float* w2_0 = (const float*)d_in[4];
  const float* b2_0 = (const float*)d_in[5];
  const float* w1_1 = (const float*)d_in[6];
  const float* b1_1 = (const float*)d_in[7];
  const float* w2_1 = (const float*)d_in[8];
  const float* b2_1 = (const float*)d_in[9];
  const float* cw1 = (const float*)d_in[10];
  const float* cb1 = (const float*)d_in[11];
  const float* cw2 = (const float*)d_in[12];
  const float* cb2 = (const float*)d_in[13];

  const int n = in_sizes[0] / 32;  // nodes (< 2^17 for packing)
  const int ne = in_sizes[1] / 2;  // edges
  const int* src = ei;
  const int* dst = ei + ne;
  const int nb = (n + NPB - 1) / NPB;

  // Workspace layout (16B-aligned uint4 region first, then ints)
  uint4* h0bf = (uint4*)d_ws;                  // n*8  (bf16 [n][64])
  uint4* xbf = h0bf + (size_t)n * 8;           // n*4  (bf16 [n][32])
  uint4* wfrag = xbf + (size_t)n * 4;          // 38*64
  int* sorted = (int*)(wfrag + 38 * 64);       // ne
  int* csr = sorted + ne;                      // ne
  int* off = csr + ne;                         // n+1
  int* bcnt = off + n + 1;                     // nb
  int* boff = bcnt + nb;                       // nb+1
  int* bcur = boff + nb + 1;                   // nb

  // prep first: zeroes bcnt, builds xbf + wfrag
  {
    const int n4 = n * 8;
    prep_kernel<<<1 + (n4 + 255) / 256, 256, 0, stream>>>(
        (const float4*)x, (uint2*)xbf, n4, w1_0, w2_0, w1_1, w2_1, cw1, cw2,
        wfrag, bcnt, nb);
  }

  // --- CSR build ---
  bucket_hist_kernel<<<220, 256, 0, stream>>>(dst, bcnt, ne, nb);
  bucket_scan_kernel<<<1, 512, 0, stream>>>(bcnt, boff, bcur, nb, ne);
  partition_kernel<<<(ne + CHUNK - 1) / CHUNK, 256, 0, stream>>>(
      src, dst, bcur, sorted, ne, nb);
  fill_bucket_kernel<<<nb, 256, 0, stream>>>(sorted, boff, off, csr, n, ne);

  const int ntile = (n + 63) / 64;
  const short8* wf = (const short8*)wfrag;

  fused0_kernel<<<ntile, 256, 0, stream>>>(xbf, off, csr, wf, b1_0, b2_0,
                                           h0bf, n);
  fused1_kernel<<<ntile, 256, 0, stream>>>(h0bf, off, csr, wf, b1_1, b2_1,
                                           cb1, cb2, (float*)d_out, n);
}

// Round 15
// 138.373 us; speedup vs baseline: 1.1141x; 1.1141x over previous
//
#include <hip/hip_runtime.h>

// ---------------------------------------------------------------------------
// TreeConv GNN. R14: edge-list split across 2 thread-teams + shfl combine.
//   R13 lesson: gather is TLP-bound (8-deep unroll -> VGPR 88, occ 17%,
//   regression). Instead halve the serial chain: 2 teams per node process
//   interleaved edge halves, combine with __shfl_xor (lane^8 / lane^4).
//   fused1: 512 thr, 32 nodes/block, 16 thr/node. fused0: 512 thr, 64
//   nodes/block, 8 thr/node. 4-deep unroll. GEMM stages on first 2(4) waves.
// ---------------------------------------------------------------------------

#define NPB 256       // nodes per bucket (fill); bucket id = dst >> 8
#define NBMAX 512     // max buckets (n <= 131072)
#define CHUNK 2048    // edges per partition block

typedef __attribute__((ext_vector_type(8))) short short8;
typedef __attribute__((ext_vector_type(4))) float f32x4;

__device__ inline unsigned int bfbits(float f) {  // RNE f32 -> bf16 bits
  unsigned int x = __float_as_uint(f);
  return (x + 0x7fffu + ((x >> 16) & 1u)) >> 16;
}
__device__ inline unsigned int packbf(float a, float b) {
  return bfbits(a) | (bfbits(b) << 16);
}
__device__ inline float bflo(unsigned int u) {
  return __uint_as_float(u << 16);
}
__device__ inline float bfhi(unsigned int u) {
  return __uint_as_float(u & 0xffff0000u);
}

// ---------------- CSR build ----------------

__global__ __launch_bounds__(256) void bucket_hist_kernel(
    const int* __restrict__ dst, int* __restrict__ bcnt, int ne, int nb) {
  __shared__ int h[NBMAX];
  for (int i = threadIdx.x; i < nb; i += 256) h[i] = 0;
  __syncthreads();
  for (int e = blockIdx.x * 256 + threadIdx.x; e < ne; e += gridDim.x * 256)
    atomicAdd(&h[dst[e] >> 8], 1);
  __syncthreads();
  for (int i = threadIdx.x; i < nb; i += 256) {
    const int c = h[i];
    if (c) atomicAdd(&bcnt[i], c);
  }
}

__global__ __launch_bounds__(512) void bucket_scan_kernel(
    const int* __restrict__ bcnt, int* __restrict__ boff,
    int* __restrict__ bcur, int nb, int ne) {
  __shared__ int wsum[8];
  const int lane = threadIdx.x & 63;
  const int wid = threadIdx.x >> 6;
  const int v = (threadIdx.x < nb) ? bcnt[threadIdx.x] : 0;
  int x = v;
#pragma unroll
  for (int s = 1; s < 64; s <<= 1) {
    int t = __shfl_up(x, s, 64);
    if (lane >= s) x += t;
  }
  if (lane == 63) wsum[wid] = x;
  __syncthreads();
  if (wid == 0 && lane < 8) {
    int y = wsum[lane];
#pragma unroll
    for (int s = 1; s < 8; s <<= 1) {
      int t = __shfl_up(y, s, 64);
      if (lane >= s) y += t;
    }
    wsum[lane] = y;
  }
  __syncthreads();
  const int wbase = (wid == 0) ? 0 : wsum[wid - 1];
  const int excl = wbase + x - v;
  if (threadIdx.x < nb) {
    boff[threadIdx.x] = excl;
    bcur[threadIdx.x] = excl;
  }
  if (threadIdx.x == 0) boff[nb] = ne;
}

__global__ __launch_bounds__(256) void partition_kernel(
    const int* __restrict__ src, const int* __restrict__ dst,
    int* __restrict__ bcur, int* __restrict__ sorted, int ne, int nb) {
  __shared__ int hist[NBMAX];
  __shared__ int lbase[NBMAX];
  __shared__ int gbase[NBMAX];
  __shared__ int cur[NBMAX];
  __shared__ int vals[CHUNK];
  __shared__ unsigned short bins[CHUNK];

  const int tid = threadIdx.x;
  const int e0 = blockIdx.x * CHUNK;
  const int m = min(CHUNK, ne - e0);

  for (int i = tid; i < nb; i += 256) hist[i] = 0;
  __syncthreads();
  for (int i = tid; i < m; i += 256) atomicAdd(&hist[dst[e0 + i] >> 8], 1);
  __syncthreads();

  if (tid < 64) {
    int v8[8];
    int tot = 0;
#pragma unroll
    for (int k = 0; k < 8; k++) {
      const int b = tid * 8 + k;
      v8[k] = (b < nb) ? hist[b] : 0;
      tot += v8[k];
    }
    int x = tot;
#pragma unroll
    for (int s = 1; s < 64; s <<= 1) {
      int t = __shfl_up(x, s, 64);
      if ((tid & 63) >= s) x += t;
    }
    int run = x - tot;
#pragma unroll
    for (int k = 0; k < 8; k++) {
      const int b = tid * 8 + k;
      if (b < nb) {
        lbase[b] = run;
        run += v8[k];
      }
    }
  }
  __syncthreads();

  for (int b = tid; b < nb; b += 256) {
    const int c = hist[b];
    cur[b] = lbase[b];
    gbase[b] = c ? atomicAdd(&bcur[b], c) : 0;
  }
  __syncthreads();

  for (int i = tid; i < m; i += 256) {
    const int s = src[e0 + i];
    const int d = dst[e0 + i];
    const int b = d >> 8;
    const int p = atomicAdd(&cur[b], 1);
    vals[p] = s | ((d & 255) << 17);
    bins[p] = (unsigned short)b;
  }
  __syncthreads();

  for (int i = tid; i < m; i += 256) {
    const int b = bins[i];
    sorted[gbase[b] + (i - lbase[b])] = vals[i];
  }
}

__global__ __launch_bounds__(256) void fill_bucket_kernel(
    const int* __restrict__ sorted, const int* __restrict__ boff,
    int* __restrict__ off, int* __restrict__ csr, int n, int ne) {
  __shared__ int hist[NPB];
  __shared__ int cur[NPB];
  __shared__ int wsum[4];
  const int tid = threadIdx.x;
  const int b = blockIdx.x;
  const int e0 = boff[b];
  const int m = boff[b + 1] - e0;

  hist[tid] = 0;
  __syncthreads();
  for (int i = tid; i < m; i += 256) atomicAdd(&hist[sorted[e0 + i] >> 17], 1);
  __syncthreads();

  const int lane = tid & 63;
  const int wid = tid >> 6;
  const int v = hist[tid];
  int x = v;
#pragma unroll
  for (int s = 1; s < 64; s <<= 1) {
    int t = __shfl_up(x, s, 64);
    if (lane >= s) x += t;
  }
  if (lane == 63) wsum[wid] = x;
  __syncthreads();
  if (tid == 0) {
    int s = 0;
#pragma unroll
    for (int k = 0; k < 4; k++) {
      const int t = wsum[k];
      wsum[k] = s;
      s += t;
    }
  }
  __syncthreads();
  const int excl = wsum[wid] + x - v;
  cur[tid] = excl;
  const int node = b * NPB + tid;
  if (node < n) off[node] = e0 + excl;
  if (b == 0 && tid == 0) off[n] = ne;
  __syncthreads();

  for (int i = tid; i < m; i += 256) {
    const int pv = sorted[e0 + i];
    const int r = atomicAdd(&cur[pv >> 17], 1);
    csr[e0 + r] = pv & 0x1FFFF;
  }
}

// ---------------------------------------------------------------------------
// prep: block 0 -> weight repack + zero bcnt; blocks 1.. -> x to bf16.
// wfrag: [0,4)=W1_0 [4,12)=W2_0 [12,20)=W1_1 [20,28)=W2_1 [28,36)=CW1
// [36,38)=CW2(N=16).
// ---------------------------------------------------------------------------
__global__ __launch_bounds__(256) void prep_kernel(
    const float4* __restrict__ x, uint2* __restrict__ xbf, int n4,
    const float* __restrict__ w1_0, const float* __restrict__ w2_0,
    const float* __restrict__ w1_1, const float* __restrict__ w2_1,
    const float* __restrict__ cw1, const float* __restrict__ cw2,
    uint4* __restrict__ wfrag, int* __restrict__ bcnt, int nb) {
  if (blockIdx.x == 0) {
    for (int i = threadIdx.x; i < nb; i += 256) bcnt[i] = 0;
    for (int idx = threadIdx.x; idx < 38 * 64; idx += 256) {
      const int f = idx >> 6, l = idx & 63;
      const float* W;
      int N = 64, f0;
      if (f < 4) { W = w1_0; f0 = f; }
      else if (f < 12) { W = w2_0; f0 = f - 4; }
      else if (f < 20) { W = w1_1; f0 = f - 12; }
      else if (f < 28) { W = w2_1; f0 = f - 20; }
      else if (f < 36) { W = cw1; f0 = f - 28; }
      else { W = cw2; f0 = f - 36; N = 16; }
      int kb, t;
      if (N == 16) { kb = f0; t = 0; } else { kb = f0 >> 2; t = f0 & 3; }
      const int k0 = kb * 32 + (l >> 4) * 8;
      const int col = t * 16 + (l & 15);
      unsigned int p[4];
#pragma unroll
      for (int j = 0; j < 4; j++)
        p[j] =
            packbf(W[(k0 + 2 * j) * N + col], W[(k0 + 2 * j + 1) * N + col]);
      wfrag[idx] = make_uint4(p[0], p[1], p[2], p[3]);
    }
    return;
  }
  const int i = (blockIdx.x - 1) * 256 + threadIdx.x;
  if (i < n4) {
    const float4 v = x[i];
    xbf[i] = make_uint2(packbf(v.x, v.y), packbf(v.z, v.w));
  }
}

// ---------------------------------------------------------------------------
// Per-wave GEMM stage on LDS tiles: wave wid handles rows [16wid,16wid+16).
// Caller guards wid and places __syncthreads() between stages.
// ---------------------------------------------------------------------------
template <int KB, int NT, bool RELU>
__device__ inline void gemm_stage(const unsigned short* __restrict__ src,
                                  int srcs, unsigned short* __restrict__ dst,
                                  const short8* __restrict__ wfrag,
                                  const float* __restrict__ bias, int wid,
                                  int lane) {
  const int l15 = lane & 15, lh = lane >> 4;
  short8 bf[KB * NT];
#pragma unroll
  for (int f = 0; f < KB * NT; f++) bf[f] = wfrag[f * 64 + lane];
  f32x4 acc[NT];
#pragma unroll
  for (int t = 0; t < NT; t++) acc[t] = (f32x4){0.f, 0.f, 0.f, 0.f};
#pragma unroll
  for (int kb = 0; kb < KB; kb++) {
    const short8 a =
        *(const short8*)&src[(wid * 16 + l15) * srcs + kb * 32 + lh * 8];
#pragma unroll
    for (int t = 0; t < NT; t++)
      acc[t] = __builtin_amdgcn_mfma_f32_16x16x32_bf16(a, bf[kb * NT + t],
                                                       acc[t], 0, 0, 0);
  }
  float bv[NT];
#pragma unroll
  for (int t = 0; t < NT; t++) bv[t] = bias[t * 16 + l15];
#pragma unroll
  for (int t = 0; t < NT; t++)
#pragma unroll
    for (int r = 0; r < 4; r++) {
      float v = acc[t][r] + bv[t];
      if (RELU) v = fmaxf(v, 0.f);
      dst[(wid * 16 + lh * 4 + r) * 72 + t * 16 + l15] =
          (unsigned short)bfbits(v);
    }
}

// ---------------------------------------------------------------------------
// fused0: gather(xbf, D=32) -> GEMM(w1_0)+relu -> GEMM(w2_0) -> h0bf.
// 512 thr, 64 nodes/block, 8 thr/node: q4 = sub&3 (uint4), h = sub>>2
// (edge half, interleaved stride-2). Combine: __shfl_xor lane^4.
// ---------------------------------------------------------------------------
__global__ __launch_bounds__(512) void fused0_kernel(
    const uint4* __restrict__ xbf, const int* __restrict__ off,
    const int* __restrict__ csr, const short8* __restrict__ wf,
    const float* __restrict__ b1, const float* __restrict__ b2,
    uint4* __restrict__ h0bf, int n) {
  __shared__ unsigned short zsA[64 * 72];
  __shared__ unsigned short zsB[64 * 72];
  const int tid = threadIdx.x;
  const int lane = tid & 63;
  const int wid = tid >> 6;
  const int n0 = blockIdx.x * 64;

  {
    const int node = tid >> 3;
    const int sub = tid & 7;
    const int q4 = sub & 3;
    const int h = sub >> 2;
    const int g = n0 + node;
    float a[8];
#pragma unroll
    for (int i = 0; i < 8; i++) a[i] = 0.f;
    if (g < n) {
      if (h == 0) {
        const uint4 u = xbf[(size_t)g * 4 + q4];
        a[0] = bflo(u.x); a[1] = bfhi(u.x); a[2] = bflo(u.y); a[3] = bfhi(u.y);
        a[4] = bflo(u.z); a[5] = bfhi(u.z); a[6] = bflo(u.w); a[7] = bfhi(u.w);
      }
      const int e0 = off[g], e1 = off[g + 1];
      int e = e0 + h;
      for (; e + 6 < e1; e += 8) {
        const int s0 = csr[e], s1 = csr[e + 2], s2 = csr[e + 4],
                  s3 = csr[e + 6];
        const uint4 u0 = xbf[(size_t)s0 * 4 + q4];
        const uint4 u1 = xbf[(size_t)s1 * 4 + q4];
        const uint4 u2 = xbf[(size_t)s2 * 4 + q4];
        const uint4 u3 = xbf[(size_t)s3 * 4 + q4];
        a[0] += bflo(u0.x) + bflo(u1.x) + bflo(u2.x) + bflo(u3.x);
        a[1] += bfhi(u0.x) + bfhi(u1.x) + bfhi(u2.x) + bfhi(u3.x);
        a[2] += bflo(u0.y) + bflo(u1.y) + bflo(u2.y) + bflo(u3.y);
        a[3] += bfhi(u0.y) + bfhi(u1.y) + bfhi(u2.y) + bfhi(u3.y);
        a[4] += bflo(u0.z) + bflo(u1.z) + bflo(u2.z) + bflo(u3.z);
        a[5] += bfhi(u0.z) + bfhi(u1.z) + bfhi(u2.z) + bfhi(u3.z);
        a[6] += bflo(u0.w) + bflo(u1.w) + bflo(u2.w) + bflo(u3.w);
        a[7] += bfhi(u0.w) + bfhi(u1.w) + bfhi(u2.w) + bfhi(u3.w);
      }
      for (; e < e1; e += 2) {
        const uint4 u4 = xbf[(size_t)csr[e] * 4 + q4];
        a[0] += bflo(u4.x); a[1] += bfhi(u4.x);
        a[2] += bflo(u4.y); a[3] += bfhi(u4.y);
        a[4] += bflo(u4.z); a[5] += bfhi(u4.z);
        a[6] += bflo(u4.w); a[7] += bfhi(u4.w);
      }
    }
    // combine edge halves (partner = lane ^ 4)
#pragma unroll
    for (int i = 0; i < 8; i++) a[i] += __shfl_xor(a[i], 4, 64);
    if (h == 0) {
      uint4 w;
      w.x = packbf(a[0], a[1]); w.y = packbf(a[2], a[3]);
      w.z = packbf(a[4], a[5]); w.w = packbf(a[6], a[7]);
      *(uint4*)&zsA[node * 40 + q4 * 8] = w;
    }
  }
  __syncthreads();
  if (wid < 4) gemm_stage<1, 4, true>(zsA, 40, zsB, wf + 0 * 64, b1, wid, lane);
  __syncthreads();
  if (wid < 4)
    gemm_stage<2, 4, false>(zsB, 72, zsA, wf + 4 * 64, b2, wid, lane);
  __syncthreads();

  for (int i = tid; i < 64 * 8; i += 512) {
    const int row = i >> 3, q = i & 7;
    if (n0 + row < n)
      ((short8*)h0bf)[(size_t)(n0 + row) * 8 + q] =
          *(const short8*)&zsA[row * 72 + q * 8];
  }
}

// ---------------------------------------------------------------------------
// fused1: gather(h0bf, D=64) -> GEMM(w1_1)+relu -> GEMM(w2_1) -> GEMM(cw1)
// +relu -> GEMM(cw2,N=16) -> out f32. 512 thr, 32 nodes/block, 16 thr/node:
// q4 = sub&7 (uint4), h = sub>>3 (edge half). Combine: __shfl_xor lane^8.
// ---------------------------------------------------------------------------
__global__ __launch_bounds__(512) void fused1_kernel(
    const uint4* __restrict__ hbf, const int* __restrict__ off,
    const int* __restrict__ csr, const short8* __restrict__ wf,
    const float* __restrict__ b1, const float* __restrict__ b2,
    const float* __restrict__ cb1, const float* __restrict__ cb2,
    float* __restrict__ out, int n) {
  __shared__ unsigned short zsA[32 * 72];
  __shared__ unsigned short zsB[32 * 72];
  const int tid = threadIdx.x;
  const int lane = tid & 63;
  const int wid = tid >> 6;
  const int n0 = blockIdx.x * 32;
  const int l15 = lane & 15, lh = lane >> 4;

  {
    const int node = tid >> 4;
    const int sub = tid & 15;
    const int q4 = sub & 7;
    const int h = sub >> 3;
    const int g = n0 + node;
    float a[8];
#pragma unroll
    for (int i = 0; i < 8; i++) a[i] = 0.f;
    if (g < n) {
      if (h == 0) {
        const uint4 u = hbf[(size_t)g * 8 + q4];
        a[0] = bflo(u.x); a[1] = bfhi(u.x); a[2] = bflo(u.y); a[3] = bfhi(u.y);
        a[4] = bflo(u.z); a[5] = bfhi(u.z); a[6] = bflo(u.w); a[7] = bfhi(u.w);
      }
      const int e0 = off[g], e1 = off[g + 1];
      int e = e0 + h;
      for (; e + 6 < e1; e += 8) {
        const int s0 = csr[e], s1 = csr[e + 2], s2 = csr[e + 4],
                  s3 = csr[e + 6];
        const uint4 u0 = hbf[(size_t)s0 * 8 + q4];
        const uint4 u1 = hbf[(size_t)s1 * 8 + q4];
        const uint4 u2 = hbf[(size_t)s2 * 8 + q4];
        const uint4 u3 = hbf[(size_t)s3 * 8 + q4];
        a[0] += bflo(u0.x) + bflo(u1.x) + bflo(u2.x) + bflo(u3.x);
        a[1] += bfhi(u0.x) + bfhi(u1.x) + bfhi(u2.x) + bfhi(u3.x);
        a[2] += bflo(u0.y) + bflo(u1.y) + bflo(u2.y) + bflo(u3.y);
        a[3] += bfhi(u0.y) + bfhi(u1.y) + bfhi(u2.y) + bfhi(u3.y);
        a[4] += bflo(u0.z) + bflo(u1.z) + bflo(u2.z) + bflo(u3.z);
        a[5] += bfhi(u0.z) + bfhi(u1.z) + bfhi(u2.z) + bfhi(u3.z);
        a[6] += bflo(u0.w) + bflo(u1.w) + bflo(u2.w) + bflo(u3.w);
        a[7] += bfhi(u0.w) + bfhi(u1.w) + bfhi(u2.w) + bfhi(u3.w);
      }
      for (; e < e1; e += 2) {
        const uint4 u4 = hbf[(size_t)csr[e] * 8 + q4];
        a[0] += bflo(u4.x); a[1] += bfhi(u4.x);
        a[2] += bflo(u4.y); a[3] += bfhi(u4.y);
        a[4] += bflo(u4.z); a[5] += bfhi(u4.z);
        a[6] += bflo(u4.w); a[7] += bfhi(u4.w);
      }
    }
    // combine edge halves (partner = lane ^ 8)
#pragma unroll
    for (int i = 0; i < 8; i++) a[i] += __shfl_xor(a[i], 8, 64);
    if (h == 0) {
      uint4 w;
      w.x = packbf(a[0], a[1]); w.y = packbf(a[2], a[3]);
      w.z = packbf(a[4], a[5]); w.w = packbf(a[6], a[7]);
      *(uint4*)&zsA[node * 72 + q4 * 8] = w;
    }
  }
  __syncthreads();
  if (wid < 2)
    gemm_stage<2, 4, true>(zsA, 72, zsB, wf + 12 * 64, b1, wid, lane);  // z1
  __syncthreads();
  if (wid < 2)
    gemm_stage<2, 4, false>(zsB, 72, zsA, wf + 20 * 64, b2, wid, lane);  // h1
  __syncthreads();
  if (wid < 2)
    gemm_stage<2, 4, true>(zsA, 72, zsB, wf + 28 * 64, cb1, wid, lane);  // z2
  __syncthreads();

  // GEMM4: K=64, N=16 (cw2) -> f32 out (waves 0-1 only)
  if (wid < 2) {
    const short8 bf0 = wf[36 * 64 + lane];
    const short8 bf1 = wf[37 * 64 + lane];
    f32x4 acc = (f32x4){0.f, 0.f, 0.f, 0.f};
#pragma unroll
    for (int kb = 0; kb < 2; kb++) {
      const short8 a =
          *(const short8*)&zsB[(wid * 16 + l15) * 72 + kb * 32 + lh * 8];
      acc = __builtin_amdgcn_mfma_f32_16x16x32_bf16(a, kb ? bf1 : bf0, acc, 0,
                                                    0, 0);
    }
    __syncthreads();
    float* zf = (float*)zsA;  // [32][20] f32
    const float bb = cb2[l15];
#pragma unroll
    for (int r = 0; r < 4; r++)
      zf[(wid * 16 + lh * 4 + r) * 20 + l15] = acc[r] + bb;
  } else {
    __syncthreads();
  }
  __syncthreads();
  {
    float* zf = (float*)zsA;
    for (int i = tid; i < 128; i += 512) {
      const int row = i >> 2, q = i & 3;
      if (n0 + row < n)
        ((float4*)out)[(size_t)(n0 + row) * 4 + q] =
            *(const float4*)&zf[row * 20 + q * 4];
    }
  }
}

extern "C" void kernel_launch(void* const* d_in, const int* in_sizes, int n_in,
                              void* d_out, int out_size, void* d_ws,
                              size_t ws_size, hipStream_t stream) {
  const float* x = (const float*)d_in[0];
  const int* ei = (const int*)d_in[1];
  const float* w1_0 = (const float*)d_in[2];
  const float* b1_0 = (const float*)d_in[3];
  const float* w2_0 = (const float*)d_in[4];
  const float* b2_0 = (const float*)d_in[5];
  const float* w1_1 = (const float*)d_in[6];
  const float* b1_1 = (const float*)d_in[7];
  const float* w2_1 = (const float*)d_in[8];
  const float* b2_1 = (const float*)d_in[9];
  const float* cw1 = (const float*)d_in[10];
  const float* cb1 = (const float*)d_in[11];
  const float* cw2 = (const float*)d_in[12];
  const float* cb2 = (const float*)d_in[13];

  const int n = in_sizes[0] / 32;  // nodes (< 2^17 for packing)
  const int ne = in_sizes[1] / 2;  // edges
  const int* src = ei;
  const int* dst = ei + ne;
  const int nb = (n + NPB - 1) / NPB;

  // Workspace layout (16B-aligned uint4 region first, then ints)
  uint4* h0bf = (uint4*)d_ws;                  // n*8  (bf16 [n][64])
  uint4* xbf = h0bf + (size_t)n * 8;           // n*4  (bf16 [n][32])
  uint4* wfrag = xbf + (size_t)n * 4;          // 38*64
  int* sorted = (int*)(wfrag + 38 * 64);       // ne
  int* csr = sorted + ne;                      // ne
  int* off = csr + ne;                         // n+1
  int* bcnt = off + n + 1;                     // nb
  int* boff = bcnt + nb;                       // nb+1
  int* bcur = boff + nb + 1;                   // nb

  // prep first: zeroes bcnt, builds xbf + wfrag
  {
    const int n4 = n * 8;
    prep_kernel<<<1 + (n4 + 255) / 256, 256, 0, stream>>>(
        (const float4*)x, (uint2*)xbf, n4, w1_0, w2_0, w1_1, w2_1, cw1, cw2,
        wfrag, bcnt, nb);
  }

  // --- CSR build ---
  bucket_hist_kernel<<<220, 256, 0, stream>>>(dst, bcnt, ne, nb);
  bucket_scan_kernel<<<1, 512, 0, stream>>>(bcnt, boff, bcur, nb, ne);
  partition_kernel<<<(ne + CHUNK - 1) / CHUNK, 256, 0, stream>>>(
      src, dst, bcur, sorted, ne, nb);
  fill_bucket_kernel<<<nb, 256, 0, stream>>>(sorted, boff, off, csr, n, ne);

  const short8* wf = (const short8*)wfrag;

  fused0_kernel<<<(n + 63) / 64, 512, 0, stream>>>(xbf, off, csr, wf, b1_0,
                                                   b2_0, h0bf, n);
  fused1_kernel<<<(n + 31) / 32, 512, 0, stream>>>(h0bf, off, csr, wf, b1_1,
                                                   b2_1, cb1, cb2,
                                                   (float*)d_out, n);
}

// Round 16
// 131.765 us; speedup vs baseline: 1.1700x; 1.0501x over previous
//
#include <hip/hip_runtime.h>

// ---------------------------------------------------------------------------
// TreeConv GNN. R15: CHUNK revert + all-wave GEMM stages.
//   R14 lessons: gather is at the random-row L3-miss structural ceiling
//   (~80MB compulsory fetch @ ~1.8TB/s) -- occupancy doubling was neutral;
//   CHUNK 2048 regressed partition (write amp). This round: CHUNK=8192,
//   and GEMM stages split across ALL 8 waves (M-tile x N-tile grid) so no
//   wave idles at barriers. Gather geometry unchanged (62% occ).
// ---------------------------------------------------------------------------

#define NPB 256       // nodes per bucket (fill); bucket id = dst >> 8
#define NBMAX 512     // max buckets (n <= 131072)
#define CHUNK 8192    // edges per partition block

typedef __attribute__((ext_vector_type(8))) short short8;
typedef __attribute__((ext_vector_type(4))) float f32x4;

__device__ inline unsigned int bfbits(float f) {  // RNE f32 -> bf16 bits
  unsigned int x = __float_as_uint(f);
  return (x + 0x7fffu + ((x >> 16) & 1u)) >> 16;
}
__device__ inline unsigned int packbf(float a, float b) {
  return bfbits(a) | (bfbits(b) << 16);
}
__device__ inline float bflo(unsigned int u) {
  return __uint_as_float(u << 16);
}
__device__ inline float bfhi(unsigned int u) {
  return __uint_as_float(u & 0xffff0000u);
}

// ---------------- CSR build ----------------

__global__ __launch_bounds__(256) void bucket_hist_kernel(
    const int* __restrict__ dst, int* __restrict__ bcnt, int ne, int nb) {
  __shared__ int h[NBMAX];
  for (int i = threadIdx.x; i < nb; i += 256) h[i] = 0;
  __syncthreads();
  for (int e = blockIdx.x * 256 + threadIdx.x; e < ne; e += gridDim.x * 256)
    atomicAdd(&h[dst[e] >> 8], 1);
  __syncthreads();
  for (int i = threadIdx.x; i < nb; i += 256) {
    const int c = h[i];
    if (c) atomicAdd(&bcnt[i], c);
  }
}

__global__ __launch_bounds__(512) void bucket_scan_kernel(
    const int* __restrict__ bcnt, int* __restrict__ boff,
    int* __restrict__ bcur, int nb, int ne) {
  __shared__ int wsum[8];
  const int lane = threadIdx.x & 63;
  const int wid = threadIdx.x >> 6;
  const int v = (threadIdx.x < nb) ? bcnt[threadIdx.x] : 0;
  int x = v;
#pragma unroll
  for (int s = 1; s < 64; s <<= 1) {
    int t = __shfl_up(x, s, 64);
    if (lane >= s) x += t;
  }
  if (lane == 63) wsum[wid] = x;
  __syncthreads();
  if (wid == 0 && lane < 8) {
    int y = wsum[lane];
#pragma unroll
    for (int s = 1; s < 8; s <<= 1) {
      int t = __shfl_up(y, s, 64);
      if (lane >= s) y += t;
    }
    wsum[lane] = y;
  }
  __syncthreads();
  const int wbase = (wid == 0) ? 0 : wsum[wid - 1];
  const int excl = wbase + x - v;
  if (threadIdx.x < nb) {
    boff[threadIdx.x] = excl;
    bcur[threadIdx.x] = excl;
  }
  if (threadIdx.x == 0) boff[nb] = ne;
}

__global__ __launch_bounds__(256) void partition_kernel(
    const int* __restrict__ src, const int* __restrict__ dst,
    int* __restrict__ bcur, int* __restrict__ sorted, int ne, int nb) {
  __shared__ int hist[NBMAX];
  __shared__ int lbase[NBMAX];
  __shared__ int gbase[NBMAX];
  __shared__ int cur[NBMAX];
  __shared__ int vals[CHUNK];
  __shared__ unsigned short bins[CHUNK];

  const int tid = threadIdx.x;
  const int e0 = blockIdx.x * CHUNK;
  const int m = min(CHUNK, ne - e0);

  for (int i = tid; i < nb; i += 256) hist[i] = 0;
  __syncthreads();
  for (int i = tid; i < m; i += 256) atomicAdd(&hist[dst[e0 + i] >> 8], 1);
  __syncthreads();

  if (tid < 64) {
    int v8[8];
    int tot = 0;
#pragma unroll
    for (int k = 0; k < 8; k++) {
      const int b = tid * 8 + k;
      v8[k] = (b < nb) ? hist[b] : 0;
      tot += v8[k];
    }
    int x = tot;
#pragma unroll
    for (int s = 1; s < 64; s <<= 1) {
      int t = __shfl_up(x, s, 64);
      if ((tid & 63) >= s) x += t;
    }
    int run = x - tot;
#pragma unroll
    for (int k = 0; k < 8; k++) {
      const int b = tid * 8 + k;
      if (b < nb) {
        lbase[b] = run;
        run += v8[k];
      }
    }
  }
  __syncthreads();

  for (int b = tid; b < nb; b += 256) {
    const int c = hist[b];
    cur[b] = lbase[b];
    gbase[b] = c ? atomicAdd(&bcur[b], c) : 0;
  }
  __syncthreads();

  for (int i = tid; i < m; i += 256) {
    const int s = src[e0 + i];
    const int d = dst[e0 + i];
    const int b = d >> 8;
    const int p = atomicAdd(&cur[b], 1);
    vals[p] = s | ((d & 255) << 17);
    bins[p] = (unsigned short)b;
  }
  __syncthreads();

  for (int i = tid; i < m; i += 256) {
    const int b = bins[i];
    sorted[gbase[b] + (i - lbase[b])] = vals[i];
  }
}

__global__ __launch_bounds__(256) void fill_bucket_kernel(
    const int* __restrict__ sorted, const int* __restrict__ boff,
    int* __restrict__ off, int* __restrict__ csr, int n, int ne) {
  __shared__ int hist[NPB];
  __shared__ int cur[NPB];
  __shared__ int wsum[4];
  const int tid = threadIdx.x;
  const int b = blockIdx.x;
  const int e0 = boff[b];
  const int m = boff[b + 1] - e0;

  hist[tid] = 0;
  __syncthreads();
  for (int i = tid; i < m; i += 256) atomicAdd(&hist[sorted[e0 + i] >> 17], 1);
  __syncthreads();

  const int lane = tid & 63;
  const int wid = tid >> 6;
  const int v = hist[tid];
  int x = v;
#pragma unroll
  for (int s = 1; s < 64; s <<= 1) {
    int t = __shfl_up(x, s, 64);
    if (lane >= s) x += t;
  }
  if (lane == 63) wsum[wid] = x;
  __syncthreads();
  if (tid == 0) {
    int s = 0;
#pragma unroll
    for (int k = 0; k < 4; k++) {
      const int t = wsum[k];
      wsum[k] = s;
      s += t;
    }
  }
  __syncthreads();
  const int excl = wsum[wid] + x - v;
  cur[tid] = excl;
  const int node = b * NPB + tid;
  if (node < n) off[node] = e0 + excl;
  if (b == 0 && tid == 0) off[n] = ne;
  __syncthreads();

  for (int i = tid; i < m; i += 256) {
    const int pv = sorted[e0 + i];
    const int r = atomicAdd(&cur[pv >> 17], 1);
    csr[e0 + r] = pv & 0x1FFFF;
  }
}

// ---------------------------------------------------------------------------
// prep: block 0 -> weight repack + zero bcnt; blocks 1.. -> x to bf16.
// wfrag: [0,4)=W1_0 [4,12)=W2_0 [12,20)=W1_1 [20,28)=W2_1 [28,36)=CW1
// [36,38)=CW2(N=16).
// ---------------------------------------------------------------------------
__global__ __launch_bounds__(256) void prep_kernel(
    const float4* __restrict__ x, uint2* __restrict__ xbf, int n4,
    const float* __restrict__ w1_0, const float* __restrict__ w2_0,
    const float* __restrict__ w1_1, const float* __restrict__ w2_1,
    const float* __restrict__ cw1, const float* __restrict__ cw2,
    uint4* __restrict__ wfrag, int* __restrict__ bcnt, int nb) {
  if (blockIdx.x == 0) {
    for (int i = threadIdx.x; i < nb; i += 256) bcnt[i] = 0;
    for (int idx = threadIdx.x; idx < 38 * 64; idx += 256) {
      const int f = idx >> 6, l = idx & 63;
      const float* W;
      int N = 64, f0;
      if (f < 4) { W = w1_0; f0 = f; }
      else if (f < 12) { W = w2_0; f0 = f - 4; }
      else if (f < 20) { W = w1_1; f0 = f - 12; }
      else if (f < 28) { W = w2_1; f0 = f - 20; }
      else if (f < 36) { W = cw1; f0 = f - 28; }
      else { W = cw2; f0 = f - 36; N = 16; }
      int kb, t;
      if (N == 16) { kb = f0; t = 0; } else { kb = f0 >> 2; t = f0 & 3; }
      const int k0 = kb * 32 + (l >> 4) * 8;
      const int col = t * 16 + (l & 15);
      unsigned int p[4];
#pragma unroll
      for (int j = 0; j < 4; j++)
        p[j] =
            packbf(W[(k0 + 2 * j) * N + col], W[(k0 + 2 * j + 1) * N + col]);
      wfrag[idx] = make_uint4(p[0], p[1], p[2], p[3]);
    }
    return;
  }
  const int i = (blockIdx.x - 1) * 256 + threadIdx.x;
  if (i < n4) {
    const float4 v = x[i];
    xbf[i] = make_uint2(packbf(v.x, v.y), packbf(v.z, v.w));
  }
}

// ---------------------------------------------------------------------------
// One wave computes NT 16x16 output tiles at (row16, tbase..tbase+NT-1) of
// D = A(LDS) @ W + bias. W frags are 4-t-strided (N=64 matrices). Caller
// places __syncthreads() between stages.
// ---------------------------------------------------------------------------
template <int KB, int NT, bool RELU>
__device__ inline void gemm_tiles(const unsigned short* __restrict__ src,
                                  int srcs, unsigned short* __restrict__ dst,
                                  const short8* __restrict__ wfrag,
                                  const float* __restrict__ bias, int row16,
                                  int tbase, int lane) {
  const int l15 = lane & 15, lh = lane >> 4;
  short8 bf[KB][NT];
#pragma unroll
  for (int kb = 0; kb < KB; kb++)
#pragma unroll
    for (int t = 0; t < NT; t++)
      bf[kb][t] = wfrag[(kb * 4 + tbase + t) * 64 + lane];
  f32x4 acc[NT];
#pragma unroll
  for (int t = 0; t < NT; t++) acc[t] = (f32x4){0.f, 0.f, 0.f, 0.f};
#pragma unroll
  for (int kb = 0; kb < KB; kb++) {
    const short8 a =
        *(const short8*)&src[(row16 * 16 + l15) * srcs + kb * 32 + lh * 8];
#pragma unroll
    for (int t = 0; t < NT; t++)
      acc[t] =
          __builtin_amdgcn_mfma_f32_16x16x32_bf16(a, bf[kb][t], acc[t], 0, 0, 0);
  }
#pragma unroll
  for (int t = 0; t < NT; t++) {
    const float bv = bias[(tbase + t) * 16 + l15];
#pragma unroll
    for (int r = 0; r < 4; r++) {
      float v = acc[t][r] + bv;
      if (RELU) v = fmaxf(v, 0.f);
      dst[(row16 * 16 + lh * 4 + r) * 72 + (tbase + t) * 16 + l15] =
          (unsigned short)bfbits(v);
    }
  }
}

// ---------------------------------------------------------------------------
// fused0: gather(xbf, D=32) -> GEMM(w1_0)+relu -> GEMM(w2_0) -> h0bf.
// 512 thr, 64 nodes/block, 8 thr/node (q4 = sub&3, h = sub>>2), shfl lane^4.
// GEMM: 8 waves, wave w -> row16 = w>>1, tbase = (w&1)*2, NT=2.
// ---------------------------------------------------------------------------
__global__ __launch_bounds__(512) void fused0_kernel(
    const uint4* __restrict__ xbf, const int* __restrict__ off,
    const int* __restrict__ csr, const short8* __restrict__ wf,
    const float* __restrict__ b1, const float* __restrict__ b2,
    uint4* __restrict__ h0bf, int n) {
  __shared__ unsigned short zsA[64 * 72];
  __shared__ unsigned short zsB[64 * 72];
  const int tid = threadIdx.x;
  const int lane = tid & 63;
  const int wid = tid >> 6;
  const int n0 = blockIdx.x * 64;

  {
    const int node = tid >> 3;
    const int sub = tid & 7;
    const int q4 = sub & 3;
    const int h = sub >> 2;
    const int g = n0 + node;
    float a[8];
#pragma unroll
    for (int i = 0; i < 8; i++) a[i] = 0.f;
    if (g < n) {
      if (h == 0) {
        const uint4 u = xbf[(size_t)g * 4 + q4];
        a[0] = bflo(u.x); a[1] = bfhi(u.x); a[2] = bflo(u.y); a[3] = bfhi(u.y);
        a[4] = bflo(u.z); a[5] = bfhi(u.z); a[6] = bflo(u.w); a[7] = bfhi(u.w);
      }
      const int e0 = off[g], e1 = off[g + 1];
      int e = e0 + h;
      for (; e + 6 < e1; e += 8) {
        const int s0 = csr[e], s1 = csr[e + 2], s2 = csr[e + 4],
                  s3 = csr[e + 6];
        const uint4 u0 = xbf[(size_t)s0 * 4 + q4];
        const uint4 u1 = xbf[(size_t)s1 * 4 + q4];
        const uint4 u2 = xbf[(size_t)s2 * 4 + q4];
        const uint4 u3 = xbf[(size_t)s3 * 4 + q4];
        a[0] += bflo(u0.x) + bflo(u1.x) + bflo(u2.x) + bflo(u3.x);
        a[1] += bfhi(u0.x) + bfhi(u1.x) + bfhi(u2.x) + bfhi(u3.x);
        a[2] += bflo(u0.y) + bflo(u1.y) + bflo(u2.y) + bflo(u3.y);
        a[3] += bfhi(u0.y) + bfhi(u1.y) + bfhi(u2.y) + bfhi(u3.y);
        a[4] += bflo(u0.z) + bflo(u1.z) + bflo(u2.z) + bflo(u3.z);
        a[5] += bfhi(u0.z) + bfhi(u1.z) + bfhi(u2.z) + bfhi(u3.z);
        a[6] += bflo(u0.w) + bflo(u1.w) + bflo(u2.w) + bflo(u3.w);
        a[7] += bfhi(u0.w) + bfhi(u1.w) + bfhi(u2.w) + bfhi(u3.w);
      }
      for (; e < e1; e += 2) {
        const uint4 u4 = xbf[(size_t)csr[e] * 4 + q4];
        a[0] += bflo(u4.x); a[1] += bfhi(u4.x);
        a[2] += bflo(u4.y); a[3] += bfhi(u4.y);
        a[4] += bflo(u4.z); a[5] += bfhi(u4.z);
        a[6] += bflo(u4.w); a[7] += bfhi(u4.w);
      }
    }
#pragma unroll
    for (int i = 0; i < 8; i++) a[i] += __shfl_xor(a[i], 4, 64);
    if (h == 0) {
      uint4 w;
      w.x = packbf(a[0], a[1]); w.y = packbf(a[2], a[3]);
      w.z = packbf(a[4], a[5]); w.w = packbf(a[6], a[7]);
      *(uint4*)&zsA[node * 40 + q4 * 8] = w;
    }
  }
  __syncthreads();
  gemm_tiles<1, 2, true>(zsA, 40, zsB, wf + 0 * 64, b1, wid >> 1,
                         (wid & 1) * 2, lane);
  __syncthreads();
  gemm_tiles<2, 2, false>(zsB, 72, zsA, wf + 4 * 64, b2, wid >> 1,
                          (wid & 1) * 2, lane);
  __syncthreads();

  for (int i = tid; i < 64 * 8; i += 512) {
    const int row = i >> 3, q = i & 7;
    if (n0 + row < n)
      ((short8*)h0bf)[(size_t)(n0 + row) * 8 + q] =
          *(const short8*)&zsA[row * 72 + q * 8];
  }
}

// ---------------------------------------------------------------------------
// fused1: gather(h0bf, D=64) -> GEMM(w1_1)+relu -> GEMM(w2_1) -> GEMM(cw1)
// +relu -> GEMM(cw2,N=16) -> out f32. 512 thr, 32 nodes/block, 16 thr/node
// (q4 = sub&7, h = sub>>3), shfl lane^8.
// GEMM stages 1-3: 8 waves, wave w -> row16 = w&1, tbase = w>>1, NT=1.
// ---------------------------------------------------------------------------
__global__ __launch_bounds__(512) void fused1_kernel(
    const uint4* __restrict__ hbf, const int* __restrict__ off,
    const int* __restrict__ csr, const short8* __restrict__ wf,
    const float* __restrict__ b1, const float* __restrict__ b2,
    const float* __restrict__ cb1, const float* __restrict__ cb2,
    float* __restrict__ out, int n) {
  __shared__ unsigned short zsA[32 * 72];
  __shared__ unsigned short zsB[32 * 72];
  const int tid = threadIdx.x;
  const int lane = tid & 63;
  const int wid = tid >> 6;
  const int n0 = blockIdx.x * 32;
  const int l15 = lane & 15, lh = lane >> 4;

  {
    const int node = tid >> 4;
    const int sub = tid & 15;
    const int q4 = sub & 7;
    const int h = sub >> 3;
    const int g = n0 + node;
    float a[8];
#pragma unroll
    for (int i = 0; i < 8; i++) a[i] = 0.f;
    if (g < n) {
      if (h == 0) {
        const uint4 u = hbf[(size_t)g * 8 + q4];
        a[0] = bflo(u.x); a[1] = bfhi(u.x); a[2] = bflo(u.y); a[3] = bfhi(u.y);
        a[4] = bflo(u.z); a[5] = bfhi(u.z); a[6] = bflo(u.w); a[7] = bfhi(u.w);
      }
      const int e0 = off[g], e1 = off[g + 1];
      int e = e0 + h;
      for (; e + 6 < e1; e += 8) {
        const int s0 = csr[e], s1 = csr[e + 2], s2 = csr[e + 4],
                  s3 = csr[e + 6];
        const uint4 u0 = hbf[(size_t)s0 * 8 + q4];
        const uint4 u1 = hbf[(size_t)s1 * 8 + q4];
        const uint4 u2 = hbf[(size_t)s2 * 8 + q4];
        const uint4 u3 = hbf[(size_t)s3 * 8 + q4];
        a[0] += bflo(u0.x) + bflo(u1.x) + bflo(u2.x) + bflo(u3.x);
        a[1] += bfhi(u0.x) + bfhi(u1.x) + bfhi(u2.x) + bfhi(u3.x);
        a[2] += bflo(u0.y) + bflo(u1.y) + bflo(u2.y) + bflo(u3.y);
        a[3] += bfhi(u0.y) + bfhi(u1.y) + bfhi(u2.y) + bfhi(u3.y);
        a[4] += bflo(u0.z) + bflo(u1.z) + bflo(u2.z) + bflo(u3.z);
        a[5] += bfhi(u0.z) + bfhi(u1.z) + bfhi(u2.z) + bfhi(u3.z);
        a[6] += bflo(u0.w) + bflo(u1.w) + bflo(u2.w) + bflo(u3.w);
        a[7] += bfhi(u0.w) + bfhi(u1.w) + bfhi(u2.w) + bfhi(u3.w);
      }
      for (; e < e1; e += 2) {
        const uint4 u4 = hbf[(size_t)csr[e] * 8 + q4];
        a[0] += bflo(u4.x); a[1] += bfhi(u4.x);
        a[2] += bflo(u4.y); a[3] += bfhi(u4.y);
        a[4] += bflo(u4.z); a[5] += bfhi(u4.z);
        a[6] += bflo(u4.w); a[7] += bfhi(u4.w);
      }
    }
#pragma unroll
    for (int i = 0; i < 8; i++) a[i] += __shfl_xor(a[i], 8, 64);
    if (h == 0) {
      uint4 w;
      w.x = packbf(a[0], a[1]); w.y = packbf(a[2], a[3]);
      w.z = packbf(a[4], a[5]); w.w = packbf(a[6], a[7]);
      *(uint4*)&zsA[node * 72 + q4 * 8] = w;
    }
  }
  __syncthreads();
  gemm_tiles<2, 1, true>(zsA, 72, zsB, wf + 12 * 64, b1, wid & 1, wid >> 1,
                         lane);  // z1
  __syncthreads();
  gemm_tiles<2, 1, false>(zsB, 72, zsA, wf + 20 * 64, b2, wid & 1, wid >> 1,
                          lane);  // h1
  __syncthreads();
  gemm_tiles<2, 1, true>(zsA, 72, zsB, wf + 28 * 64, cb1, wid & 1, wid >> 1,
                         lane);  // z2
  __syncthreads();

  // GEMM4: K=64, N=16 (cw2) -> f32 out (2 M-tiles on waves 0-1)
  f32x4 acc = (f32x4){0.f, 0.f, 0.f, 0.f};
  if (wid < 2) {
    const short8 bf0 = wf[36 * 64 + lane];
    const short8 bf1 = wf[37 * 64 + lane];
#pragma unroll
    for (int kb = 0; kb < 2; kb++) {
      const short8 a =
          *(const short8*)&zsB[(wid * 16 + l15) * 72 + kb * 32 + lh * 8];
      acc = __builtin_amdgcn_mfma_f32_16x16x32_bf16(a, kb ? bf1 : bf0, acc, 0,
                                                    0, 0);
    }
  }
  __syncthreads();
  if (wid < 2) {
    float* zf = (float*)zsA;  // [32][20] f32
    const float bb = cb2[l15];
#pragma unroll
    for (int r = 0; r < 4; r++)
      zf[(wid * 16 + lh * 4 + r) * 20 + l15] = acc[r] + bb;
  }
  __syncthreads();
  {
    float* zf = (float*)zsA;
    for (int i = tid; i < 128; i += 512) {
      const int row = i >> 2, q = i & 3;
      if (n0 + row < n)
        ((float4*)out)[(size_t)(n0 + row) * 4 + q] =
            *(const float4*)&zf[row * 20 + q * 4];
    }
  }
}

extern "C" void kernel_launch(void* const* d_in, const int* in_sizes, int n_in,
                              void* d_out, int out_size, void* d_ws,
                              size_t ws_size, hipStream_t stream) {
  const float* x = (const float*)d_in[0];
  const int* ei = (const int*)d_in[1];
  const float* w1_0 = (const float*)d_in[2];
  const float* b1_0 = (const float*)d_in[3];
  const float* w2_0 = (const float*)d_in[4];
  const float* b2_0 = (const float*)d_in[5];
  const float* w1_1 = (const float*)d_in[6];
  const float* b1_1 = (const float*)d_in[7];
  const float* w2_1 = (const float*)d_in[8];
  const float* b2_1 = (const float*)d_in[9];
  const float* cw1 = (const float*)d_in[10];
  const float* cb1 = (const float*)d_in[11];
  const float* cw2 = (const float*)d_in[12];
  const float* cb2 = (const float*)d_in[13];

  const int n = in_sizes[0] / 32;  // nodes (< 2^17 for packing)
  const int ne = in_sizes[1] / 2;  // edges
  const int* src = ei;
  const int* dst = ei + ne;
  const int nb = (n + NPB - 1) / NPB;

  // Workspace layout (16B-aligned uint4 region first, then ints)
  uint4* h0bf = (uint4*)d_ws;                  // n*8  (bf16 [n][64])
  uint4* xbf = h0bf + (size_t)n * 8;           // n*4  (bf16 [n][32])
  uint4* wfrag = xbf + (size_t)n * 4;          // 38*64
  int* sorted = (int*)(wfrag + 38 * 64);       // ne
  int* csr = sorted + ne;                      // ne
  int* off = csr + ne;                         // n+1
  int* bcnt = off + n + 1;                     // nb
  int* boff = bcnt + nb;                       // nb+1
  int* bcur = boff + nb + 1;                   // nb

  // prep first: zeroes bcnt, builds xbf + wfrag
  {
    const int n4 = n * 8;
    prep_kernel<<<1 + (n4 + 255) / 256, 256, 0, stream>>>(
        (const float4*)x, (uint2*)xbf, n4, w1_0, w2_0, w1_1, w2_1, cw1, cw2,
        wfrag, bcnt, nb);
  }

  // --- CSR build ---
  bucket_hist_kernel<<<220, 256, 0, stream>>>(dst, bcnt, ne, nb);
  bucket_scan_kernel<<<1, 512, 0, stream>>>(bcnt, boff, bcur, nb, ne);
  partition_kernel<<<(ne + CHUNK - 1) / CHUNK, 256, 0, stream>>>(
      src, dst, bcur, sorted, ne, nb);
  fill_bucket_kernel<<<nb, 256, 0, stream>>>(sorted, boff, off, csr, n, ne);

  const short8* wf = (const short8*)wfrag;

  fused0_kernel<<<(n + 63) / 64, 512, 0, stream>>>(xbf, off, csr, wf, b1_0,
                                                   b2_0, h0bf, n);
  fused1_kernel<<<(n + 31) / 32, 512, 0, stream>>>(h0bf, off, csr, wf, b1_1,
                                                   b2_1, cb1, cb2,
                                                   (float*)d_out, n);
}